// Round 5
// baseline (1050.023 us; speedup 1.0000x reference)
//
#include <hip/hip_runtime.h>

namespace {

typedef float v2f __attribute__((ext_vector_type(2)));

constexpr int T_SEQ = 2048;
constexpr int B_SZ  = 512;
constexpr int C_IN  = 8;
constexpr int H_SZ  = 20;
constexpr int PH    = 8;                   // x steps per phase-register
constexpr int N_PH  = T_SEQ / PH;          // 256
constexpr float LOG2E = 1.44269504088896340736f;

__device__ __forceinline__ float rlane(float v, int lane) {
  return __int_as_float(__builtin_amdgcn_readlane(__float_as_int(v), lane));
}

template<int S>
__device__ __forceinline__ float quad_bcast(float v) {
  return __int_as_float(__builtin_amdgcn_update_dpp(
      __float_as_int(v), __float_as_int(v), S * 0x55, 0xF, 0xF, true));
}

__device__ __forceinline__ v2f fma2(v2f a, v2f b, v2f c) {
  return __builtin_elementwise_fma(a, b, c);   // v_pk_fma_f32
}
__device__ __forceinline__ v2f splat2(float s) { v2f r; r.x = s; r.y = s; return r; }
__device__ __forceinline__ v2f zero2() { v2f r; r.x = 0.f; r.y = 0.f; return r; }

// Both gate sets: sigmoid (g!=2) / tanh (g==2); cm has log2e pre-folded.
__device__ __forceinline__ v2f act2(v2f a, float cm, float am, float ad) {
  float ex = __builtin_amdgcn_exp2f(a.x * cm);
  float ey = __builtin_amdgcn_exp2f(a.y * cm);
  float sx = __builtin_amdgcn_rcpf(1.0f + ex);
  float sy = __builtin_amdgcn_rcpf(1.0f + ey);
  v2f r; r.x = __fmaf_rn(sx, am, ad); r.y = __fmaf_rn(sy, am, ad);
  return r;
}

__device__ __forceinline__ float fast_tanh(float a) {
  float e = __builtin_amdgcn_exp2f(a * (-2.0f * LOG2E));
  float s = __builtin_amdgcn_rcpf(1.0f + e);
  return __fmaf_rn(s, 2.0f, -1.0f);
}

// h[k] broadcast from quad-distributed regs (set1 at lanes 4k for k<16;
// set2 value for k=16..19 replicated, take lane 4*(k-16)).
#define H_BC(ha, hb, k) (((k) < 16) ? rlane((ha), 4 * (k)) : rlane((hb), 4 * ((k) - 16)))

__global__ __attribute__((amdgpu_flat_work_group_size(64, 64),
                          amdgpu_waves_per_eu(1, 1)))
void lstm2_one(const float* __restrict__ x,
               const float* __restrict__ Wih0, const float* __restrict__ Whh0,
               const float* __restrict__ bih0, const float* __restrict__ bhh0,
               const float* __restrict__ Wih1, const float* __restrict__ Whh1,
               const float* __restrict__ bih1, const float* __restrict__ bhh1,
               float* __restrict__ out)
{
  const int l  = threadIdx.x & 63;
  const int b  = blockIdx.x;
  const int k1 = l >> 2;             // 0..15
  const int g  = l & 3;              // 0=i 1=f 2=g 3=o
  const int k2 = 16 + (k1 & 3);      // 16..19 (replicated)
  const int j1 = g * H_SZ + k1;
  const int j2 = g * H_SZ + k2;

  const bool  isg = (g == 2);
  const float cm  = isg ? (-2.0f * LOG2E) : (-LOG2E);
  const float am  = isg ?  2.0f : 1.0f;
  const float ad  = isg ? -1.0f : 0.0f;

  // ---- weights, all gate-set packed: {row j1, row j2} ----
  v2f wx[C_IN], wh[H_SZ], wy[H_SZ], wq[H_SZ];
#pragma unroll
  for (int c = 0; c < C_IN; ++c) {
    wx[c].x = Wih0[j1 * C_IN + c]; wx[c].y = Wih0[j2 * C_IN + c];
  }
#pragma unroll
  for (int k = 0; k < H_SZ; ++k) {
    wh[k].x = Whh0[j1 * H_SZ + k]; wh[k].y = Whh0[j2 * H_SZ + k];
    wy[k].x = Wih1[j1 * H_SZ + k]; wy[k].y = Wih1[j2 * H_SZ + k];
    wq[k].x = Whh1[j1 * H_SZ + k]; wq[k].y = Whh1[j2 * H_SZ + k];
  }
  v2f b0; b0.x = bih0[j1] + bhh0[j1]; b0.y = bih0[j2] + bhh0[j2];
  v2f b1; b1.x = bih1[j1] + bhh1[j1]; b1.y = bih1[j2] + bhh1[j2];

  // ---- states ----
  float h0a = 0.f, h0b = 0.f, c0a = 0.f, c0b = 0.f;
  float h1a = 0.f, h1b = 0.f, c1a = 0.f, c1b = 0.f;

  // ---- x stream: lane l holds x[t = 8p + (l>>3)][ch l&7], 1 reg per phase ----
  const float* xl = x + (size_t)(l >> 3) * (B_SZ * C_IN)
                      + (size_t)b * C_IN + (l & 7);
  const size_t phstr = (size_t)PH * B_SZ * C_IN;
  float xc = xl[0];                  // phase 0 (in flight during weight load)
  float xn = xl[phstr];              // phase 1

  // ---- store machinery: 20 active lanes, per-lane constant column ----
  const bool do_store = (g == 0) || (g == 1 && k1 < 4);
  const int  col      = (g == 0) ? k1 : (16 + k1);
  float* op = out + (size_t)b * H_SZ;

  auto l0_step = [&](const float (&SX)[C_IN], const float (&SH)[H_SZ]) {
    v2f A0 = b0, A1 = zero2(), A2 = zero2(), A3 = zero2();
#pragma unroll
    for (int c = 0; c < C_IN; c += 4) {
      A0 = fma2(wx[c],     splat2(SX[c]),     A0);
      A1 = fma2(wx[c + 1], splat2(SX[c + 1]), A1);
      A2 = fma2(wx[c + 2], splat2(SX[c + 2]), A2);
      A3 = fma2(wx[c + 3], splat2(SX[c + 3]), A3);
    }
#pragma unroll
    for (int k = 0; k < H_SZ; k += 4) {
      A0 = fma2(wh[k],     splat2(SH[k]),     A0);
      A1 = fma2(wh[k + 1], splat2(SH[k + 1]), A1);
      A2 = fma2(wh[k + 2], splat2(SH[k + 2]), A2);
      A3 = fma2(wh[k + 3], splat2(SH[k + 3]), A3);
    }
    v2f A = (A0 + A1) + (A2 + A3);
    v2f act = act2(A, cm, am, ad);
    float iv = quad_bcast<0>(act.x), fv = quad_bcast<1>(act.x);
    float gv = quad_bcast<2>(act.x), ov = quad_bcast<3>(act.x);
    c0a = __fmaf_rn(fv, c0a, iv * gv);
    h0a = ov * fast_tanh(c0a);
    iv = quad_bcast<0>(act.y); fv = quad_bcast<1>(act.y);
    gv = quad_bcast<2>(act.y); ov = quad_bcast<3>(act.y);
    c0b = __fmaf_rn(fv, c0b, iv * gv);
    h0b = ov * fast_tanh(c0b);
  };

  // L1 step m: y = h0(m) broadcasts (shared with L0's iter m+1), q = h1(m-1).
  auto l1_step = [&](const float (&SH)[H_SZ], const float (&SQ)[H_SZ]) {
    v2f A0 = b1, A1 = zero2(), A2 = zero2(), A3 = zero2();
#pragma unroll
    for (int k = 0; k < H_SZ; k += 2) {
      A0 = fma2(wy[k],     splat2(SH[k]),     A0);
      A1 = fma2(wy[k + 1], splat2(SH[k + 1]), A1);
      A2 = fma2(wq[k],     splat2(SQ[k]),     A2);
      A3 = fma2(wq[k + 1], splat2(SQ[k + 1]), A3);
    }
    v2f A = (A0 + A1) + (A2 + A3);
    v2f act = act2(A, cm, am, ad);
    float iv = quad_bcast<0>(act.x), fv = quad_bcast<1>(act.x);
    float gv = quad_bcast<2>(act.x), ov = quad_bcast<3>(act.x);
    c1a = __fmaf_rn(fv, c1a, iv * gv);
    h1a = ov * fast_tanh(c1a);
    iv = quad_bcast<0>(act.y); fv = quad_bcast<1>(act.y);
    gv = quad_bcast<2>(act.y); ov = quad_bcast<3>(act.y);
    c1b = __fmaf_rn(fv, c1b, iv * gv);
    h1b = ov * fast_tanh(c1b);

    float sv = (g == 0) ? h1a : h1b;
    if (do_store) op[col] = sv;      // fire-and-forget, never drained in-loop
    op += (size_t)B_SZ * H_SZ;
  };

  // ---- peel n = 0: L0 only, h0(-1) = 0 ----
  {
    float SX[C_IN];
#pragma unroll
    for (int c = 0; c < C_IN; ++c) SX[c] = rlane(xc, c);
    float SH[H_SZ];
#pragma unroll
    for (int k = 0; k < H_SZ; ++k) SH[k] = 0.f;
    l0_step(SX, SH);
  }

  // ---- main: iterations n = 1 .. T-1 (L0 step n, L1 step n-1) ----
#pragma unroll 1
  for (int p = 0; p < N_PH; ++p) {
    if (p > 0) {
      xc = xn;                                     // phase p's x
      if (p + 1 < N_PH) xn = xl[(size_t)(p + 1) * phstr];  // in flight 1 phase
    }
#pragma unroll
    for (int j = 0; j < PH; ++j) {
      if (j == 0 && p == 0) continue;              // n=0 handled by peel
      float SH[H_SZ], SQ[H_SZ], SX[C_IN];
#pragma unroll
      for (int k = 0; k < H_SZ; ++k) {
        SH[k] = H_BC(h0a, h0b, k);                 // h0(n-1), pre-update
        SQ[k] = H_BC(h1a, h1b, k);                 // h1(n-2), pre-update
      }
#pragma unroll
      for (int c = 0; c < C_IN; ++c) SX[c] = rlane(xc, j * 8 + c);  // imm lane
      l0_step(SX, SH);                             // -> h0(n)
      l1_step(SH, SQ);                             // -> h1(n-1), store out[n-1]
    }
  }

  // ---- tail: L1 step T-1 ----
  {
    float SH[H_SZ], SQ[H_SZ];
#pragma unroll
    for (int k = 0; k < H_SZ; ++k) {
      SH[k] = H_BC(h0a, h0b, k);                   // h0(T-1)
      SQ[k] = H_BC(h1a, h1b, k);                   // h1(T-2)
    }
    l1_step(SH, SQ);                               // store out[T-1]
  }
}

} // namespace

extern "C" void kernel_launch(void* const* d_in, const int* in_sizes, int n_in,
                              void* d_out, int out_size, void* d_ws, size_t ws_size,
                              hipStream_t stream) {
  const float* x    = (const float*)d_in[0];
  const float* Wih0 = (const float*)d_in[1];
  const float* Whh0 = (const float*)d_in[2];
  const float* bih0 = (const float*)d_in[3];
  const float* bhh0 = (const float*)d_in[4];
  const float* Wih1 = (const float*)d_in[5];
  const float* Whh1 = (const float*)d_in[6];
  const float* bih1 = (const float*)d_in[7];
  const float* bhh1 = (const float*)d_in[8];
  float* out = (float*)d_out;

  hipLaunchKernelGGL(lstm2_one, dim3(B_SZ), dim3(64), 0, stream,
                     x, Wih0, Whh0, bih0, bhh0, Wih1, Whh1, bih1, bhh1, out);
}

// Round 6
// 761.525 us; speedup vs baseline: 1.3788x; 1.3788x over previous
//
#include <hip/hip_runtime.h>

namespace {

typedef float v2f __attribute__((ext_vector_type(2)));

constexpr int T_SEQ = 2048;
constexpr int B_SZ  = 512;
constexpr int C_IN  = 8;
constexpr int H_SZ  = 20;
constexpr int P_LEN = 32;                 // steps per phase (barrier period)
constexpr int N_PH  = T_SEQ / P_LEN;      // 64 phases
constexpr int RING  = 2 * P_LEN;          // 64-slot h0 handoff ring
constexpr float LOG2E = 1.44269504088896340736f;

template<int S>
__device__ __forceinline__ float quad_bcast(float v) {
  return __int_as_float(__builtin_amdgcn_update_dpp(
      __float_as_int(v), __float_as_int(v), S * 0x55, 0xF, 0xF, true));
}

__device__ __forceinline__ v2f fma2(v2f a, v2f b, v2f c) {
  return __builtin_elementwise_fma(a, b, c);   // v_pk_fma_f32, all-VGPR operands
}
__device__ __forceinline__ v2f zero2() { v2f r; r.x = 0.f; r.y = 0.f; return r; }

// G = {gate set1, gate set2}; sigmoid (g!=2) / tanh (g==2); cm has log2e folded.
__device__ __forceinline__ v2f act2(v2f a, float cm, float am, float ad) {
  float ex = __builtin_amdgcn_exp2f(a.x * cm);
  float ey = __builtin_amdgcn_exp2f(a.y * cm);
  float sx = __builtin_amdgcn_rcpf(1.0f + ex);
  float sy = __builtin_amdgcn_rcpf(1.0f + ey);
  v2f r; r.x = __fmaf_rn(sx, am, ad); r.y = __fmaf_rn(sy, am, ad);
  return r;
}

__device__ __forceinline__ float fast_tanh(float a) {
  float e = __builtin_amdgcn_exp2f(a * (-2.0f * LOG2E));
  float s = __builtin_amdgcn_rcpf(1.0f + e);
  return __fmaf_rn(s, 2.0f, -1.0f);
}

__global__ __attribute__((amdgpu_flat_work_group_size(128, 128),
                          amdgpu_waves_per_eu(1, 1)))
void lstm2_lds(const float* __restrict__ x,
               const float* __restrict__ Wih0, const float* __restrict__ Whh0,
               const float* __restrict__ bih0, const float* __restrict__ bhh0,
               const float* __restrict__ Wih1, const float* __restrict__ Whh1,
               const float* __restrict__ bih1, const float* __restrict__ bhh1,
               float* __restrict__ out)
{
  // h0 handoff ring: 64 steps (2 phases), 20 floats/slot (80 B rows).
  __shared__ __align__(16) float hbuf[RING][H_SZ];
  // wave1-private h1 ping-pong (wave-internal, never barrier-protected).
  __shared__ __align__(16) float h1buf[2][H_SZ];
  // x staging: double buffer, 32 steps x 8 ch = 256 floats per phase.
  __shared__ __align__(16) float xbuf[2][P_LEN * C_IN];

  const int tid = threadIdx.x;
  const int wv  = tid >> 6;          // 0 = layer-0 wave, 1 = layer-1 wave
  const int l   = tid & 63;
  const int b   = blockIdx.x;
  const int k1  = l >> 2;            // 0..15
  const int g   = l & 3;             // gate slot: 0=i 1=f 2=g 3=o
  const int k2  = 16 + (k1 & 3);     // 16..19 (replicated)
  const int j1  = g * H_SZ + k1;
  const int j2  = g * H_SZ + k2;

  const bool  isg = (g == 2);
  const float cm  = isg ? (-2.0f * LOG2E) : (-LOG2E);
  const float am  = isg ?  2.0f : 1.0f;
  const float ad  = isg ? -1.0f : 0.0f;

  if (wv == 0) {
    // ================= layer-0 producer wave =================
    // Weights k-paired per row: pk_fma(w_pair, operand_pair, acc) — no splats.
    v2f wx1[C_IN / 2], wx2[C_IN / 2];     // Wih0 rows j1 / j2
    v2f wh1[H_SZ / 2], wh2[H_SZ / 2];     // Whh0 rows j1 / j2
#pragma unroll
    for (int t = 0; t < C_IN / 2; ++t) {
      wx1[t].x = Wih0[j1 * C_IN + 2 * t]; wx1[t].y = Wih0[j1 * C_IN + 2 * t + 1];
      wx2[t].x = Wih0[j2 * C_IN + 2 * t]; wx2[t].y = Wih0[j2 * C_IN + 2 * t + 1];
    }
#pragma unroll
    for (int t = 0; t < H_SZ / 2; ++t) {
      wh1[t].x = Whh0[j1 * H_SZ + 2 * t]; wh1[t].y = Whh0[j1 * H_SZ + 2 * t + 1];
      wh2[t].x = Whh0[j2 * H_SZ + 2 * t]; wh2[t].y = Whh0[j2 * H_SZ + 2 * t + 1];
    }
    const float bs1 = bih0[j1] + bhh0[j1];
    const float bs2 = bih0[j2] + bhh0[j2];

    float ca = 0.f, cb = 0.f;

    // h0(-1) = 0: wave0 self-initializes the slot read at n=0.
    if (l < H_SZ) hbuf[RING - 1][l] = 0.f;

    // x stream: lane l covers phase element e = l + 64u (u=0..3);
    // t = 32p + (l>>3) + 8u, ch = l&7.
    const float* xl = x + (size_t)(l >> 3) * (B_SZ * C_IN)
                        + (size_t)b * C_IN + (l & 7);
    const size_t ustr  = (size_t)8 * B_SZ * C_IN;
    const size_t phstr = (size_t)P_LEN * B_SZ * C_IN;
    {   // phase 0 committed now (same-wave use only)
      float a0 = xl[0], a1 = xl[ustr], a2 = xl[2 * ustr], a3 = xl[3 * ustr];
      xbuf[0][l] = a0; xbuf[0][64 + l] = a1;
      xbuf[0][128 + l] = a2; xbuf[0][192 + l] = a3;
    }
    float xr0 = xl[phstr], xr1 = xl[phstr + ustr],
          xr2 = xl[phstr + 2 * ustr], xr3 = xl[phstr + 3 * ustr];

    for (int p = 0; p <= N_PH; ++p) {
      if (p < N_PH) {
        const int buf = p & 1;
        for (int j = 0; j < P_LEN; ++j) {
          const int n = p * P_LEN + j;
          const v2f* xp = (const v2f*)&xbuf[buf][j * C_IN];
          const v2f* hp = (const v2f*)hbuf[(n + RING - 1) & (RING - 1)];

          v2f A0, A1, A2, A3;
          A0.x = bs1; A0.y = 0.f; A1 = zero2();
          A2.x = bs2; A2.y = 0.f; A3 = zero2();
          // x-dot first (xbuf read latency overlaps h-read issue)
          A0 = fma2(wx1[0], xp[0], A0);  A2 = fma2(wx2[0], xp[0], A2);
          A1 = fma2(wx1[1], xp[1], A1);  A3 = fma2(wx2[1], xp[1], A3);
          A0 = fma2(wx1[2], xp[2], A0);  A2 = fma2(wx2[2], xp[2], A2);
          A1 = fma2(wx1[3], xp[3], A1);  A3 = fma2(wx2[3], xp[3], A3);
          // recurrent h-dot, vector-paired from LDS
#pragma unroll
          for (int t = 0; t < H_SZ / 2; t += 2) {
            A0 = fma2(wh1[t],     hp[t],     A0);
            A2 = fma2(wh2[t],     hp[t],     A2);
            A1 = fma2(wh1[t + 1], hp[t + 1], A1);
            A3 = fma2(wh2[t + 1], hp[t + 1], A3);
          }
          v2f S1 = A0 + A1, S2 = A2 + A3;
          v2f G; G.x = S1.x + S1.y; G.y = S2.x + S2.y;

          v2f act = act2(G, cm, am, ad);
          float iv = quad_bcast<0>(act.x), fv = quad_bcast<1>(act.x);
          float gv = quad_bcast<2>(act.x), ov = quad_bcast<3>(act.x);
          ca = __fmaf_rn(fv, ca, iv * gv);
          float ha = ov * fast_tanh(ca);
          iv = quad_bcast<0>(act.y); fv = quad_bcast<1>(act.y);
          gv = quad_bcast<2>(act.y); ov = quad_bcast<3>(act.y);
          cb = __fmaf_rn(fv, cb, iv * gv);
          float hb = ov * fast_tanh(cb);

          const int slot = n & (RING - 1);
          if (g == 0) {
            hbuf[slot][k1] = ha;                   // k 0..15
            if (k1 < 4) hbuf[slot][16 + k1] = hb;  // k 16..19
          }
        }
        // Commit next phase's x (loads in flight ~32 steps); issue p+2 loads.
        if (p + 1 < N_PH) {
          const int nb = (p + 1) & 1;
          xbuf[nb][l] = xr0; xbuf[nb][64 + l] = xr1;
          xbuf[nb][128 + l] = xr2; xbuf[nb][192 + l] = xr3;
        }
        if (p + 2 < N_PH) {
          const size_t o = (size_t)(p + 2) * phstr;
          xr0 = xl[o]; xr1 = xl[o + ustr];
          xr2 = xl[o + 2 * ustr]; xr3 = xl[o + 3 * ustr];
        }
      }
      __syncthreads();   // 65 barriers total, both waves
    }
  } else {
    // ================= layer-1 consumer wave (lags one phase) =================
    v2f wy1[H_SZ / 2], wy2[H_SZ / 2];     // Wih1 rows j1 / j2
    v2f wq1[H_SZ / 2], wq2[H_SZ / 2];     // Whh1 rows j1 / j2
#pragma unroll
    for (int t = 0; t < H_SZ / 2; ++t) {
      wy1[t].x = Wih1[j1 * H_SZ + 2 * t]; wy1[t].y = Wih1[j1 * H_SZ + 2 * t + 1];
      wy2[t].x = Wih1[j2 * H_SZ + 2 * t]; wy2[t].y = Wih1[j2 * H_SZ + 2 * t + 1];
      wq1[t].x = Whh1[j1 * H_SZ + 2 * t]; wq1[t].y = Whh1[j1 * H_SZ + 2 * t + 1];
      wq2[t].x = Whh1[j2 * H_SZ + 2 * t]; wq2[t].y = Whh1[j2 * H_SZ + 2 * t + 1];
    }
    const float bs1 = bih1[j1] + bhh1[j1];
    const float bs2 = bih1[j2] + bhh1[j2];

    float ca = 0.f, cb = 0.f;
    float* op = out + (size_t)b * H_SZ;

    // h1(-1) = 0: step m reads slot (m+1)&1, so m=0 reads slot 1.
    if (l < H_SZ) h1buf[1][l] = 0.f;

    for (int p = 0; p <= N_PH; ++p) {
      if (p >= 1) {
        const int base = (p - 1) * P_LEN;
        for (int j = 0; j < P_LEN; ++j) {
          const int m = base + j;
          const v2f* yp = (const v2f*)hbuf[m & (RING - 1)];    // h0(m)
          const v2f* qp = (const v2f*)h1buf[(m + 1) & 1];      // h1(m-1)

          v2f A0, A1, A2, A3, A4, A5, A6, A7;
          A0.x = bs1; A0.y = 0.f; A1 = zero2(); A2 = zero2(); A3 = zero2();
          A4.x = bs2; A4.y = 0.f; A5 = zero2(); A6 = zero2(); A7 = zero2();
#pragma unroll
          for (int t = 0; t < H_SZ / 2; t += 2) {
            A0 = fma2(wy1[t],     yp[t],     A0);
            A4 = fma2(wy2[t],     yp[t],     A4);
            A1 = fma2(wy1[t + 1], yp[t + 1], A1);
            A5 = fma2(wy2[t + 1], yp[t + 1], A5);
            A2 = fma2(wq1[t],     qp[t],     A2);
            A6 = fma2(wq2[t],     qp[t],     A6);
            A3 = fma2(wq1[t + 1], qp[t + 1], A3);
            A7 = fma2(wq2[t + 1], qp[t + 1], A7);
          }
          v2f S1 = (A0 + A1) + (A2 + A3);
          v2f S2 = (A4 + A5) + (A6 + A7);
          v2f G; G.x = S1.x + S1.y; G.y = S2.x + S2.y;

          v2f act = act2(G, cm, am, ad);
          float iv = quad_bcast<0>(act.x), fv = quad_bcast<1>(act.x);
          float gv = quad_bcast<2>(act.x), ov = quad_bcast<3>(act.x);
          ca = __fmaf_rn(fv, ca, iv * gv);
          float ha = ov * fast_tanh(ca);
          iv = quad_bcast<0>(act.y); fv = quad_bcast<1>(act.y);
          gv = quad_bcast<2>(act.y); ov = quad_bcast<3>(act.y);
          cb = __fmaf_rn(fv, cb, iv * gv);
          float hb = ov * fast_tanh(cb);

          if (g == 0) {
            h1buf[m & 1][k1] = ha;                   // recurrence for m+1
            if (k1 < 4) h1buf[m & 1][16 + k1] = hb;
            op[k1] = ha;                             // out[m, b, 0..15]
            if (k1 < 4) op[16 + k1] = hb;            // out[m, b, 16..19]
          }
          op += (size_t)B_SZ * H_SZ;
        }
      }
      __syncthreads();
    }
  }
}

} // namespace

extern "C" void kernel_launch(void* const* d_in, const int* in_sizes, int n_in,
                              void* d_out, int out_size, void* d_ws, size_t ws_size,
                              hipStream_t stream) {
  const float* x    = (const float*)d_in[0];
  const float* Wih0 = (const float*)d_in[1];
  const float* Whh0 = (const float*)d_in[2];
  const float* bih0 = (const float*)d_in[3];
  const float* bhh0 = (const float*)d_in[4];
  const float* Wih1 = (const float*)d_in[5];
  const float* Whh1 = (const float*)d_in[6];
  const float* bih1 = (const float*)d_in[7];
  const float* bhh1 = (const float*)d_in[8];
  float* out = (float*)d_out;

  hipLaunchKernelGGL(lstm2_lds, dim3(B_SZ), dim3(128), 0, stream,
                     x, Wih0, Whh0, bih0, bhh0, Wih1, Whh1, bih1, bhh1, out);
}